// Round 8
// baseline (316.315 us; speedup 1.0000x reference)
//
#include <hip/hip_runtime.h>
#include <hip/hip_bf16.h>
#include <math.h>

#define E 768
#define NH 12
#define HD 64

typedef __attribute__((ext_vector_type(8))) short bf16x8;
typedef __attribute__((ext_vector_type(4))) float f32x4;

__device__ __forceinline__ unsigned short f2bf_rne(float f) {
    unsigned int u = __float_as_uint(f);
    u += 0x7FFF + ((u >> 16) & 1);   // round-to-nearest-even
    return (unsigned short)(u >> 16);
}

// ---------------------------------------------------------------------------
// Fused pre kernel — ALL segments wide (R5 lesson: no low-parallelism tails).
//   seg0: conv spw   fp32->bf16        (576 blocks, float4)
//   seg1: conv [Wk;Wv] fp32->bf16      (1152 blocks)
//   seg2: trilinear sample -> bf16     (B*P = 2048 blocks)
//   seg3: q = bio @ Wq^T + bq          (3072 blocks, wave-per-output matvec)
//   seg4: zero aout                    (48 blocks)
// ---------------------------------------------------------------------------
__global__ __launch_bounds__(256) void fused_pre(
    const float* __restrict__ spw, const float* __restrict__ ipw,
    const float* __restrict__ ipb, const float* __restrict__ x,
    const float* __restrict__ bcrd, const float* __restrict__ offs,
    const int* __restrict__ gsize, const float* __restrict__ bio,
    unsigned short* __restrict__ spw_bf, unsigned short* __restrict__ kvw_bf,
    unsigned short* __restrict__ sampled, float* __restrict__ q,
    float* __restrict__ aout,
    int B, int P, int fullN, int nb_conv1, int nb_conv2, int nb_qproj)
{
    int blk = blockIdx.x;
    int t = threadIdx.x;

    if (blk < nb_conv1) {
        int i = blk * 256 + t;
        float4 v = ((const float4*)spw)[i];
        ushort4 o;
        o.x = f2bf_rne(v.x); o.y = f2bf_rne(v.y);
        o.z = f2bf_rne(v.z); o.w = f2bf_rne(v.w);
        ((ushort4*)spw_bf)[i] = o;
        return;
    }
    blk -= nb_conv1;
    if (blk < nb_conv2) {
        int i = blk * 256 + t;
        float4 v = ((const float4*)(ipw + (size_t)E * E))[i];
        ushort4 o;
        o.x = f2bf_rne(v.x); o.y = f2bf_rne(v.y);
        o.z = f2bf_rne(v.z); o.w = f2bf_rne(v.w);
        ((ushort4*)kvw_bf)[i] = o;
        return;
    }
    blk -= nb_conv2;
    if (blk < B * P) {
        // ---- trilinear border sample (coalesced float4 row reads) ----
        int bp = blk;
        int b = bp / P, p = bp % P;
        int G = *gsize;
        float gm1 = (float)(G - 1);

        float cx = bcrd[p * 3 + 0] + offs[bp * 3 + 0];
        float cy = bcrd[p * 3 + 1] + offs[bp * 3 + 1];
        float cz = bcrd[p * 3 + 2] + offs[bp * 3 + 2];
        cx = fminf(fmaxf(cx, -1.f), 1.f);
        cy = fminf(fmaxf(cy, -1.f), 1.f);
        cz = fminf(fmaxf(cz, -1.f), 1.f);

        float ix = (cx + 1.f) * 0.5f * gm1;
        float iy = (cy + 1.f) * 0.5f * gm1;
        float iz = (cz + 1.f) * 0.5f * gm1;
        float fx = floorf(ix), fy = floorf(iy), fz = floorf(iz);
        float wx = ix - fx, wy = iy - fy, wz = iz - fz;

        int x0 = (int)fminf(fmaxf(fx,       0.f), gm1);
        int x1 = (int)fminf(fmaxf(fx + 1.f, 0.f), gm1);
        int y0 = (int)fminf(fmaxf(fy,       0.f), gm1);
        int y1 = (int)fminf(fmaxf(fy + 1.f, 0.f), gm1);
        int z0 = (int)fminf(fmaxf(fz,       0.f), gm1);
        int z1 = (int)fminf(fmaxf(fz + 1.f, 0.f), gm1);

        int tk[8];
        tk[0] = (z0 * G + y0) * G + x0;
        tk[1] = (z0 * G + y0) * G + x1;
        tk[2] = (z0 * G + y1) * G + x0;
        tk[3] = (z0 * G + y1) * G + x1;
        tk[4] = (z1 * G + y0) * G + x0;
        tk[5] = (z1 * G + y0) * G + x1;
        tk[6] = (z1 * G + y1) * G + x0;
        tk[7] = (z1 * G + y1) * G + x1;
        float wgt[8];
        wgt[0] = (1.f - wz) * (1.f - wy) * (1.f - wx);
        wgt[1] = (1.f - wz) * (1.f - wy) * wx;
        wgt[2] = (1.f - wz) * wy * (1.f - wx);
        wgt[3] = (1.f - wz) * wy * wx;
        wgt[4] = wz * (1.f - wy) * (1.f - wx);
        wgt[5] = wz * (1.f - wy) * wx;
        wgt[6] = wz * wy * (1.f - wx);
        wgt[7] = wz * wy * wx;

        const float4* xb4 = (const float4*)(x + ((size_t)b * fullN + 1) * E);
        ushort4* outp = (ushort4*)(sampled + (size_t)bp * E);
        for (int c4 = t; c4 < E / 4; c4 += 256) {
            float4 acc = {0.f, 0.f, 0.f, 0.f};
#pragma unroll
            for (int k = 0; k < 8; ++k) {
                float4 v = xb4[(size_t)tk[k] * (E / 4) + c4];
                acc.x += wgt[k] * v.x; acc.y += wgt[k] * v.y;
                acc.z += wgt[k] * v.z; acc.w += wgt[k] * v.w;
            }
            ushort4 o;
            o.x = f2bf_rne(acc.x); o.y = f2bf_rne(acc.y);
            o.z = f2bf_rne(acc.z); o.w = f2bf_rne(acc.w);
            outp[c4] = o;
        }
        return;
    }
    blk -= B * P;
    if (blk < nb_qproj) {
        // ---- q projection, wave-per-output (matvec_nt shape, proven) ----
        int wid = blk * 4 + (t >> 6);          // 0 .. B*E-1
        int ln = t & 63;
        int m = wid / E, n = wid % E;
        const float* a = bio + (size_t)m * E;
        const float* w = ipw + (size_t)n * E;
        float s = 0.f;
        for (int k = ln; k < E; k += 64) s += a[k] * w[k];
#pragma unroll
        for (int off = 32; off; off >>= 1) s += __shfl_down(s, off);
        if (ln == 0) q[wid] = s + ipb[n];
        return;
    }
    blk -= nb_qproj;
    {
        // ---- zero aout (B*E floats = 12288 float4 = 48 blocks) ----
        int i = blk * 256 + t;
        float4 z = {0.f, 0.f, 0.f, 0.f};
        ((float4*)aout)[i] = z;
    }
}

// ---------------------------------------------------------------------------
// bf16 MFMA NT GEMM (m97 structure, unchanged — proven correct/fast).
// ---------------------------------------------------------------------------
template <bool OUT_BF16>
__global__ __launch_bounds__(256) void gemm_bf16_nt(
    const unsigned short* __restrict__ A,
    const unsigned short* __restrict__ W,
    const float* __restrict__ bias,
    void* __restrict__ C,
    int M, int N, int K)
{
    __shared__ unsigned short lsA[128 * 32];
    __shared__ unsigned short lsB[128 * 32];

    int wv = threadIdx.x >> 6;
    int ln = threadIdx.x & 63;
    int m0 = blockIdx.y * 128;
    int n0 = blockIdx.x * 128;
    int wm = (wv & 1) * 64;
    int wn = (wv >> 1) * 64;

    f32x4 acc[4][4] = {};

    int srow = ln >> 2;
    int scol = (ln & 3) * 8;

    for (int k0 = 0; k0 < K; k0 += 32) {
#pragma unroll
        for (int c = 0; c < 2; ++c) {
            int chunk = wv * 2 + c;
            int row = chunk * 16 + srow;
            const unsigned short* ga = A + (size_t)(m0 + row) * K + k0 + scol;
            const unsigned short* gw = W + (size_t)(n0 + row) * K + k0 + scol;
            __builtin_amdgcn_global_load_lds(
                (const __attribute__((address_space(1))) unsigned int*)ga,
                (__attribute__((address_space(3))) unsigned int*)(lsA + chunk * 16 * 32),
                16, 0, 0);
            __builtin_amdgcn_global_load_lds(
                (const __attribute__((address_space(1))) unsigned int*)gw,
                (__attribute__((address_space(3))) unsigned int*)(lsB + chunk * 16 * 32),
                16, 0, 0);
        }
        __syncthreads();

        int kq = (ln >> 4) * 8;
        int rsel = ln & 15;
        bf16x8 af[4], bfr[4];
#pragma unroll
        for (int i = 0; i < 4; ++i) {
            af[i]  = *(const bf16x8*)&lsA[(wm + i * 16 + rsel) * 32 + kq];
            bfr[i] = *(const bf16x8*)&lsB[(wn + i * 16 + rsel) * 32 + kq];
        }
#pragma unroll
        for (int i = 0; i < 4; ++i)
#pragma unroll
            for (int j = 0; j < 4; ++j)
                acc[i][j] = __builtin_amdgcn_mfma_f32_16x16x32_bf16(
                    af[i], bfr[j], acc[i][j], 0, 0, 0);
        __syncthreads();
    }

    int cr = (ln >> 4) * 4;
    int cc = ln & 15;
#pragma unroll
    for (int j = 0; j < 4; ++j) {
        int col = n0 + wn + j * 16 + cc;
        float bv = bias[col];
#pragma unroll
        for (int i = 0; i < 4; ++i) {
#pragma unroll
            for (int r = 0; r < 4; ++r) {
                int row = m0 + wm + i * 16 + cr + r;
                float v = acc[i][j][r] + bv;
                if (OUT_BF16)
                    ((unsigned short*)C)[(size_t)row * N + col] = f2bf_rne(v);
                else
                    ((float*)C)[(size_t)row * N + col] = v;
            }
        }
    }
}

// ---------------------------------------------------------------------------
// Fused attention + out_proj partials. One 64-thread block per (b,h).
// scores -> softmax -> ctx_h (LDS) -> atomicAdd per-head out_proj partial
// into pre-zeroed aout (bias applied later in bcast).
// ---------------------------------------------------------------------------
__global__ void attn_op_kernel(const float* __restrict__ q,
                               const float* __restrict__ kv,
                               const float* __restrict__ opw,
                               float* __restrict__ aout,
                               int B, int P)
{
    int bh = blockIdx.x;
    int b = bh / NH, h = bh % NH;
    int d = threadIdx.x;  // 0..63

    __shared__ float qs[HD];
    __shared__ float sc[64];
    __shared__ float cv[HD];

    qs[d] = q[(size_t)b * E + h * HD + d];
    __syncthreads();

    if (d < P) {
        const float* kr = kv + ((size_t)(b * P + d)) * (2 * E) + h * HD;
        float s = 0.f;
#pragma unroll
        for (int e = 0; e < HD; ++e) s += qs[e] * kr[e];
        sc[d] = s * 0.125f;  // 1/sqrt(64)
    }
    __syncthreads();

    float mx = -INFINITY;
    for (int p = 0; p < P; ++p) mx = fmaxf(mx, sc[p]);
    float den = 0.f;
    for (int p = 0; p < P; ++p) den += __expf(sc[p] - mx);
    __syncthreads();
    if (d < P) sc[d] = __expf(sc[d] - mx) / den;
    __syncthreads();

    float acc = 0.f;
    for (int p = 0; p < P; ++p)
        acc += sc[p] * kv[((size_t)(b * P + p)) * (2 * E) + E + h * HD + d];
    cv[d] = acc;
    __syncthreads();

    // out_proj partial: aout[b,n] += dot(cv, opw[n, h*64 : h*64+64])
    float* ab = aout + (size_t)b * E;
#pragma unroll
    for (int nn = 0; nn < E / 64; ++nn) {
        int n = nn * 64 + d;
        const float4* w4 = (const float4*)(opw + (size_t)n * E + h * HD);
        float s = 0.f;
#pragma unroll
        for (int k4 = 0; k4 < HD / 4; ++k4) {
            float4 w = w4[k4];
            s += w.x * cv[k4 * 4] + w.y * cv[k4 * 4 + 1]
               + w.z * cv[k4 * 4 + 2] + w.w * cv[k4 * 4 + 3];
        }
        atomicAdd(&ab[n], s);
    }
}

// ---------------------------------------------------------------------------
// out[b,n,c] = (aout[b,c] + opb[c]) * conf[b]   (101 MB, HBM-bound write;
// overwrites ALL of d_out incl. earlier scratch — aout lives in d_ws)
// ---------------------------------------------------------------------------
__global__ void bcast_kernel(const float* __restrict__ aout,
                             const float* __restrict__ opb,
                             const float* __restrict__ conf,
                             float* __restrict__ out,
                             int fullN, int pc)
{
    int b = blockIdx.y;
    float cf = conf[b];
    const float4* ao = (const float4*)(aout + (size_t)b * E);
    const float4* bo = (const float4*)opb;
    float4* ob = (float4*)(out + (size_t)b * fullN * E);
    int i = blockIdx.x * blockDim.x + threadIdx.x;
    if (i < pc) {
        int c4 = i % (E / 4);
        float4 v = ao[c4];
        float4 bb = bo[c4];
        v.x = (v.x + bb.x) * cf; v.y = (v.y + bb.y) * cf;
        v.z = (v.z + bb.z) * cf; v.w = (v.w + bb.w) * cf;
        ob[i] = v;
    }
}

// ---------------------------------------------------------------------------
extern "C" void kernel_launch(void* const* d_in, const int* in_sizes, int n_in,
                              void* d_out, int out_size, void* d_ws, size_t ws_size,
                              hipStream_t stream)
{
    const float* x      = (const float*)d_in[0];
    const float* bio    = (const float*)d_in[1];
    const float* bcrd   = (const float*)d_in[2];
    const float* offs   = (const float*)d_in[3];
    const float* conf   = (const float*)d_in[4];
    const float* spw    = (const float*)d_in[5];
    const float* spb    = (const float*)d_in[6];
    const float* ipw    = (const float*)d_in[7];
    const float* ipb    = (const float*)d_in[8];
    const float* opw    = (const float*)d_in[9];
    const float* opb    = (const float*)d_in[10];
    const int*   gsize  = (const int*)d_in[11];
    float* out = (float*)d_out;

    const int B     = in_sizes[1] / E;            // 64
    const int P     = in_sizes[2] / 3;            // 32
    const int fullN = in_sizes[0] / (B * E);      // 513
    const int M     = B * P;                      // 2048

    // Scratch in d_out's front (~22.6 of 100.8 MB); bcast overwrites all last.
    char* base = (char*)d_out;
    unsigned short* sampled_bf = (unsigned short*)(base + 0);          // 3.0 MB
    unsigned short* sproj_bf   = (unsigned short*)(base + 3145728);    // 3.0 MB
    unsigned short* spw_bf     = (unsigned short*)(base + 6291456);    // 1.125 MB
    unsigned short* ipwkv_bf   = (unsigned short*)(base + 7471104);    // 2.25 MB
    float*          kv         = (float*)(base + 9830400);             // 12.6 MB
    float*          q          = (float*)(base + 22413312);            // 192 KB
    float*          aout       = (float*)d_ws;                         // 192 KB

    // 1. fused pre: convs + sampling + q-proj (wave-per-output) + zero-aout
    int nb_conv1 = (E * E) / 1024;        // 576
    int nb_conv2 = (2 * E * E) / 1024;    // 1152
    int nb_qproj = (B * E) / 4;           // 12288 waves / 4 per block = 3072
    int nb_zero  = (B * E) / 1024;        // 48
    int nblocks  = nb_conv1 + nb_conv2 + M + nb_qproj + nb_zero;
    fused_pre<<<nblocks, 256, 0, stream>>>(spw, ipw, ipb, x, bcrd, offs, gsize, bio,
                                           spw_bf, ipwkv_bf, sampled_bf, q, aout,
                                           B, P, fullN, nb_conv1, nb_conv2, nb_qproj);

    // 2. sproj = sampled @ spw^T + spb  (2048 x 768, K=768) -> bf16
    gemm_bf16_nt<true><<<dim3(E / 128, M / 128), 256, 0, stream>>>(
        sampled_bf, spw_bf, spb, sproj_bf, M, E, E);

    // 3. kv = sproj @ [Wk;Wv]^T + [bk;bv]  (2048 x 1536, K=768) -> fp32
    gemm_bf16_nt<false><<<dim3(2 * E / 128, M / 128), 256, 0, stream>>>(
        sproj_bf, ipwkv_bf, ipb + E, kv, M, 2 * E, E);

    // 4. fused attention + out_proj partials (atomic accumulate into aout)
    attn_op_kernel<<<B * NH, 64, 0, stream>>>(q, kv, opw, aout, B, P);

    // 5. broadcast: (aout + opb) * confidence  (overwrites all of d_out)
    int pc = fullN * E / 4;
    bcast_kernel<<<dim3((pc + 255) / 256, B), 256, 0, stream>>>(aout, opb, conf,
                                                                out, fullN, pc);
}

// Round 9
// 305.619 us; speedup vs baseline: 1.0350x; 1.0350x over previous
//
#include <hip/hip_runtime.h>
#include <hip/hip_bf16.h>
#include <math.h>

#define E 768
#define NH 12
#define HD 64

typedef __attribute__((ext_vector_type(8))) short bf16x8;
typedef __attribute__((ext_vector_type(4))) float f32x4;

__device__ __forceinline__ unsigned short f2bf_rne(float f) {
    unsigned int u = __float_as_uint(f);
    u += 0x7FFF + ((u >> 16) & 1);   // round-to-nearest-even
    return (unsigned short)(u >> 16);
}

// ---------------------------------------------------------------------------
// Fused convs + sampling. All segments wide (3776 blocks). Best-measured
// configuration (R7: 305.6 us total).
//   seg0: conv spw   fp32->bf16   (576 blocks, float4)
//   seg1: conv [Wk;Wv] fp32->bf16 (1152 blocks)
//   seg2: trilinear sample -> bf16 (B*P = 2048 blocks)
// ---------------------------------------------------------------------------
__global__ __launch_bounds__(256) void fused_conv_sample(
    const float* __restrict__ spw, const float* __restrict__ ipw,
    const float* __restrict__ x,
    const float* __restrict__ bcrd, const float* __restrict__ offs,
    const int* __restrict__ gsize,
    unsigned short* __restrict__ spw_bf, unsigned short* __restrict__ kvw_bf,
    unsigned short* __restrict__ sampled,
    int B, int P, int fullN, int nb_conv1, int nb_conv2)
{
    int blk = blockIdx.x;
    int t = threadIdx.x;

    if (blk < nb_conv1) {
        int i = blk * 256 + t;
        float4 v = ((const float4*)spw)[i];
        ushort4 o;
        o.x = f2bf_rne(v.x); o.y = f2bf_rne(v.y);
        o.z = f2bf_rne(v.z); o.w = f2bf_rne(v.w);
        ((ushort4*)spw_bf)[i] = o;
        return;
    }
    blk -= nb_conv1;
    if (blk < nb_conv2) {
        int i = blk * 256 + t;
        float4 v = ((const float4*)(ipw + (size_t)E * E))[i];
        ushort4 o;
        o.x = f2bf_rne(v.x); o.y = f2bf_rne(v.y);
        o.z = f2bf_rne(v.z); o.w = f2bf_rne(v.w);
        ((ushort4*)kvw_bf)[i] = o;
        return;
    }
    blk -= nb_conv2;
    {
        int bp = blk;
        int b = bp / P, p = bp % P;
        int G = *gsize;
        float gm1 = (float)(G - 1);

        float cx = bcrd[p * 3 + 0] + offs[bp * 3 + 0];
        float cy = bcrd[p * 3 + 1] + offs[bp * 3 + 1];
        float cz = bcrd[p * 3 + 2] + offs[bp * 3 + 2];
        cx = fminf(fmaxf(cx, -1.f), 1.f);
        cy = fminf(fmaxf(cy, -1.f), 1.f);
        cz = fminf(fmaxf(cz, -1.f), 1.f);

        float ix = (cx + 1.f) * 0.5f * gm1;
        float iy = (cy + 1.f) * 0.5f * gm1;
        float iz = (cz + 1.f) * 0.5f * gm1;
        float fx = floorf(ix), fy = floorf(iy), fz = floorf(iz);
        float wx = ix - fx, wy = iy - fy, wz = iz - fz;

        int x0 = (int)fminf(fmaxf(fx,       0.f), gm1);
        int x1 = (int)fminf(fmaxf(fx + 1.f, 0.f), gm1);
        int y0 = (int)fminf(fmaxf(fy,       0.f), gm1);
        int y1 = (int)fminf(fmaxf(fy + 1.f, 0.f), gm1);
        int z0 = (int)fminf(fmaxf(fz,       0.f), gm1);
        int z1 = (int)fminf(fmaxf(fz + 1.f, 0.f), gm1);

        int tk[8];
        tk[0] = (z0 * G + y0) * G + x0;
        tk[1] = (z0 * G + y0) * G + x1;
        tk[2] = (z0 * G + y1) * G + x0;
        tk[3] = (z0 * G + y1) * G + x1;
        tk[4] = (z1 * G + y0) * G + x0;
        tk[5] = (z1 * G + y0) * G + x1;
        tk[6] = (z1 * G + y1) * G + x0;
        tk[7] = (z1 * G + y1) * G + x1;
        float wgt[8];
        wgt[0] = (1.f - wz) * (1.f - wy) * (1.f - wx);
        wgt[1] = (1.f - wz) * (1.f - wy) * wx;
        wgt[2] = (1.f - wz) * wy * (1.f - wx);
        wgt[3] = (1.f - wz) * wy * wx;
        wgt[4] = wz * (1.f - wy) * (1.f - wx);
        wgt[5] = wz * (1.f - wy) * wx;
        wgt[6] = wz * wy * (1.f - wx);
        wgt[7] = wz * wy * wx;

        const float4* xb4 = (const float4*)(x + ((size_t)b * fullN + 1) * E);
        ushort4* outp = (ushort4*)(sampled + (size_t)bp * E);
        for (int c4 = t; c4 < E / 4; c4 += 256) {
            float4 acc = {0.f, 0.f, 0.f, 0.f};
#pragma unroll
            for (int k = 0; k < 8; ++k) {
                float4 v = xb4[(size_t)tk[k] * (E / 4) + c4];
                acc.x += wgt[k] * v.x; acc.y += wgt[k] * v.y;
                acc.z += wgt[k] * v.z; acc.w += wgt[k] * v.w;
            }
            ushort4 o;
            o.x = f2bf_rne(acc.x); o.y = f2bf_rne(acc.y);
            o.z = f2bf_rne(acc.z); o.w = f2bf_rne(acc.w);
            outp[c4] = o;
        }
    }
}

// ---------------------------------------------------------------------------
// bf16 MFMA NT GEMM (m97 structure — proven correct/fast).
// ---------------------------------------------------------------------------
template <bool OUT_BF16>
__global__ __launch_bounds__(256) void gemm_bf16_nt(
    const unsigned short* __restrict__ A,
    const unsigned short* __restrict__ W,
    const float* __restrict__ bias,
    void* __restrict__ C,
    int M, int N, int K)
{
    __shared__ unsigned short lsA[128 * 32];
    __shared__ unsigned short lsB[128 * 32];

    int wv = threadIdx.x >> 6;
    int ln = threadIdx.x & 63;
    int m0 = blockIdx.y * 128;
    int n0 = blockIdx.x * 128;
    int wm = (wv & 1) * 64;
    int wn = (wv >> 1) * 64;

    f32x4 acc[4][4] = {};

    int srow = ln >> 2;
    int scol = (ln & 3) * 8;

    for (int k0 = 0; k0 < K; k0 += 32) {
#pragma unroll
        for (int c = 0; c < 2; ++c) {
            int chunk = wv * 2 + c;
            int row = chunk * 16 + srow;
            const unsigned short* ga = A + (size_t)(m0 + row) * K + k0 + scol;
            const unsigned short* gw = W + (size_t)(n0 + row) * K + k0 + scol;
            __builtin_amdgcn_global_load_lds(
                (const __attribute__((address_space(1))) unsigned int*)ga,
                (__attribute__((address_space(3))) unsigned int*)(lsA + chunk * 16 * 32),
                16, 0, 0);
            __builtin_amdgcn_global_load_lds(
                (const __attribute__((address_space(1))) unsigned int*)gw,
                (__attribute__((address_space(3))) unsigned int*)(lsB + chunk * 16 * 32),
                16, 0, 0);
        }
        __syncthreads();

        int kq = (ln >> 4) * 8;
        int rsel = ln & 15;
        bf16x8 af[4], bfr[4];
#pragma unroll
        for (int i = 0; i < 4; ++i) {
            af[i]  = *(const bf16x8*)&lsA[(wm + i * 16 + rsel) * 32 + kq];
            bfr[i] = *(const bf16x8*)&lsB[(wn + i * 16 + rsel) * 32 + kq];
        }
#pragma unroll
        for (int i = 0; i < 4; ++i)
#pragma unroll
            for (int j = 0; j < 4; ++j)
                acc[i][j] = __builtin_amdgcn_mfma_f32_16x16x32_bf16(
                    af[i], bfr[j], acc[i][j], 0, 0, 0);
        __syncthreads();
    }

    int cr = (ln >> 4) * 4;
    int cc = ln & 15;
#pragma unroll
    for (int j = 0; j < 4; ++j) {
        int col = n0 + wn + j * 16 + cc;
        float bv = bias[col];
#pragma unroll
        for (int i = 0; i < 4; ++i) {
#pragma unroll
            for (int r = 0; r < 4; ++r) {
                int row = m0 + wm + i * 16 + cr + r;
                float v = acc[i][j][r] + bv;
                if (OUT_BF16)
                    ((unsigned short*)C)[(size_t)row * N + col] = f2bf_rne(v);
                else
                    ((float*)C)[(size_t)row * N + col] = v;
            }
        }
    }
}

// ---------------------------------------------------------------------------
// Small-M fp32 GEMM: one wave per output element, lane-strided (coalesced)
// reads, shuffle reduction.
// ---------------------------------------------------------------------------
__global__ void matvec_nt(const float* __restrict__ A,
                          const float* __restrict__ W,
                          const float* __restrict__ bias,
                          float* __restrict__ C,
                          int M, int N, int K)
{
    int wid = blockIdx.x * (blockDim.x >> 6) + (threadIdx.x >> 6);
    int ln = threadIdx.x & 63;
    if (wid >= M * N) return;
    int m = wid / N, n = wid % N;
    const float* a = A + (size_t)m * K;
    const float* w = W + (size_t)n * K;
    float s = 0.f;
    for (int k = ln; k < K; k += 64) s += a[k] * w[k];
#pragma unroll
    for (int off = 32; off; off >>= 1) s += __shfl_down(s, off);
    if (ln == 0) C[wid] = s + bias[n];
}

// ---------------------------------------------------------------------------
// Per-(b,h) attention over P points. kv rows: [k(768) | v(768)], fp32.
// ---------------------------------------------------------------------------
__global__ void attn_kernel(const float* __restrict__ q,
                            const float* __restrict__ kv,
                            float* __restrict__ ctx,
                            int B, int P)
{
    int bh = blockIdx.x;
    int b = bh / NH, h = bh % NH;
    int d = threadIdx.x;  // 0..63

    __shared__ float qs[HD];
    __shared__ float sc[64];

    qs[d] = q[(size_t)b * E + h * HD + d];
    __syncthreads();

    if (d < P) {
        const float* kr = kv + ((size_t)(b * P + d)) * (2 * E) + h * HD;
        float s = 0.f;
#pragma unroll
        for (int e = 0; e < HD; ++e) s += qs[e] * kr[e];
        sc[d] = s * 0.125f;
    }
    __syncthreads();

    float mx = -INFINITY;
    for (int p = 0; p < P; ++p) mx = fmaxf(mx, sc[p]);
    float den = 0.f;
    for (int p = 0; p < P; ++p) den += __expf(sc[p] - mx);
    __syncthreads();
    if (d < P) sc[d] = __expf(sc[d] - mx) / den;
    __syncthreads();

    float acc = 0.f;
    for (int p = 0; p < P; ++p)
        acc += sc[p] * kv[((size_t)(b * P + p)) * (2 * E) + E + h * HD + d];
    ctx[(size_t)b * E + h * HD + d] = acc;
}

// ---------------------------------------------------------------------------
// out[b,n,c] = attn_out[b,c] * conf[b]  (101 MB, HBM-bound; overwrites ALL
// of d_out including earlier scratch — aout lives in d_ws, no race)
// ---------------------------------------------------------------------------
__global__ void bcast_kernel(const float* __restrict__ attn_out,
                             const float* __restrict__ conf,
                             float* __restrict__ out,
                             int fullN, int pc)
{
    int b = blockIdx.y;
    float cf = conf[b];
    const float4* ao = (const float4*)(attn_out + (size_t)b * E);
    float4* ob = (float4*)(out + (size_t)b * fullN * E);
    int i = blockIdx.x * blockDim.x + threadIdx.x;
    if (i < pc) {
        int c4 = i % (E / 4);
        float4 v = ao[c4];
        v.x *= cf; v.y *= cf; v.z *= cf; v.w *= cf;
        ob[i] = v;
    }
}

// ---------------------------------------------------------------------------
extern "C" void kernel_launch(void* const* d_in, const int* in_sizes, int n_in,
                              void* d_out, int out_size, void* d_ws, size_t ws_size,
                              hipStream_t stream)
{
    const float* x      = (const float*)d_in[0];
    const float* bio    = (const float*)d_in[1];
    const float* bcrd   = (const float*)d_in[2];
    const float* offs   = (const float*)d_in[3];
    const float* conf   = (const float*)d_in[4];
    const float* spw    = (const float*)d_in[5];
    const float* spb    = (const float*)d_in[6];
    const float* ipw    = (const float*)d_in[7];
    const float* ipb    = (const float*)d_in[8];
    const float* opw    = (const float*)d_in[9];
    const float* opb    = (const float*)d_in[10];
    const int*   gsize  = (const int*)d_in[11];
    float* out = (float*)d_out;

    const int B     = in_sizes[1] / E;            // 64
    const int P     = in_sizes[2] / 3;            // 32
    const int fullN = in_sizes[0] / (B * E);      // 513
    const int M     = B * P;                      // 2048

    // Scratch in d_out's front (~22.6 of 100.8 MB); bcast overwrites all last.
    char* base = (char*)d_out;
    unsigned short* sampled_bf = (unsigned short*)(base + 0);          // 3.0 MB
    unsigned short* sproj_bf   = (unsigned short*)(base + 3145728);    // 3.0 MB
    unsigned short* spw_bf     = (unsigned short*)(base + 6291456);    // 1.125 MB
    unsigned short* ipwkv_bf   = (unsigned short*)(base + 7471104);    // 2.25 MB
    float*          kv         = (float*)(base + 9830400);             // 12.6 MB
    float*          q          = (float*)(base + 22413312);            // 192 KB
    float*          ctx        = (float*)(base + 22609920);            // 192 KB
    float*          aout       = (float*)d_ws;                         // 192 KB

    // 1. fused convs + sampling (all segments wide; no low-parallelism tail)
    int nb_conv1 = (E * E) / 1024;        // 576
    int nb_conv2 = (2 * E * E) / 1024;    // 1152
    int nblocks  = nb_conv1 + nb_conv2 + M;
    fused_conv_sample<<<nblocks, 256, 0, stream>>>(spw, ipw, x, bcrd, offs, gsize,
                                                   spw_bf, ipwkv_bf, sampled_bf,
                                                   B, P, fullN, nb_conv1, nb_conv2);

    // 2. sproj = sampled @ spw^T + spb  (2048 x 768, K=768) -> bf16
    gemm_bf16_nt<true><<<dim3(E / 128, M / 128), 256, 0, stream>>>(
        sampled_bf, spw_bf, spb, sproj_bf, M, E, E);

    // 3. kv = sproj @ [Wk;Wv]^T + [bk;bv]  (2048 x 1536, K=768) -> fp32
    gemm_bf16_nt<false><<<dim3(2 * E / 128, M / 128), 256, 0, stream>>>(
        sproj_bf, ipwkv_bf, ipb + E, kv, M, 2 * E, E);

    // 4. q = bio @ Wq^T + bq  (64 x 768, fp32, wave-per-output — proven fast)
    {
        int tot = B * E;
        matvec_nt<<<(tot + 3) / 4, 256, 0, stream>>>(bio, ipw, ipb, q, B, E, E);
    }

    // 5. attention
    attn_kernel<<<B * NH, 64, 0, stream>>>(q, kv, ctx, B, P);

    // 6. aout = ctx @ out_proj_w^T + opb  (64 x 768, fp32)
    {
        int tot = B * E;
        matvec_nt<<<(tot + 3) / 4, 256, 0, stream>>>(ctx, opw, opb, aout, B, E, E);
    }

    // 7. broadcast * confidence (overwrites every element of d_out)
    int pc = fullN * E / 4;
    bcast_kernel<<<dim3((pc + 255) / 256, B), 256, 0, stream>>>(aout, conf, out, fullN, pc);
}